// Round 7
// baseline (212.490 us; speedup 1.0000x reference)
//
#include <hip/hip_runtime.h>
#include <math.h>

// Problem constants (fixed by the reference).
#define BB    1024
#define SS    277
#define RR    76
#define ZZ    56
#define NLHS  24
#define NROWS (BB*SS)                      // 283648
#define ROWS_PER_BLOCK 256                 // rows per group (reduction unit, bit-exact)
#define NBCE (NROWS/ROWS_PER_BLOCK)        // 1108 groups
#define NMOM ZZ                            // 56 mom partials (first in layout)
#define NBLK (NBCE + NMOM)                 // 1164 partials (layout unchanged)
#define F4ROW 19                           // 76 floats = 19 float4 per row
#define BLK_ELEMS (ROWS_PER_BLOCK*RR)      // 19456
#define ROWS_PER_WAVE 64
#define F4WAVE (ROWS_PER_WAVE*F4ROW)       // 1216 float4 per wave
#define NMASK (NLHS*RR)                    // 1824
#define TOTAL_ELEMS 21558272.0             // harness-verified constant

static_assert(NROWS % ROWS_PER_BLOCK == 0, "rows divide groups");

#define LN2F  0.69314718056f
#define NLN2F (-144.26950409f)   /* -100 / ln2 */

// Opaque 16B global load (R9-proven): compiler cannot rematerialize/re-read
// the result, so the 19 row float4s stay resident (VGPR/AGPR). Consumption
// fenced by s_waitcnt vmcnt(0) + sched_barrier(0) (rule #18).
__device__ __forceinline__ float4 gload16(const float* p) {
    float4 r;
    asm volatile("global_load_dwordx4 %0, %1, off"
                 : "=v"(r)
                 : "v"((unsigned long long)p));
    return r;
}

// R10: R9 minus redundant bytes. Evidence: all five structures (R4-R9)
// converge to 2.4-2.8 TB/s effective READ rate; m13's "6.29 TB/s copy" is
// read+write traffic, i.e. ~3.15 TB/s read share -> R9 is at ~90% of the
// demonstrated read ceiling. Only lever left: traffic. Masks re-reads were
// 32MB/iter (15%) rebuilding an identical 384B bitmap per wave. A 1-block
// setup kernel builds it once into workspace; BCE threads gather 3 words +
// ind_to_lhs[true_r] directly (L1-hot, 6 lines). Bit semantics, scan, math,
// reduce tree, partials layout verbatim R9 -> bit-identical output.

// ---------------------------------------------------------------------------
// Setup: build the 24x96-bit mask bitmap once. mb[lhs*4 + (r>>5)] bit (r&31)
// = masks[lhs*RR + r] > 0.5f  — identical semantics to the old per-wave pack.
// ---------------------------------------------------------------------------
__global__ __launch_bounds__(256) void setup_kernel(
    const float* __restrict__ masks,
    unsigned int* __restrict__ mb)
{
    __shared__ unsigned int smb[NLHS*4];
    const int tid = threadIdx.x;
    if (tid < NLHS*4) smb[tid] = 0u;
    __syncthreads();
    for (int e = tid; e < NMASK; e += 256) {
        const int lhs = e / RR;
        const int r   = e - lhs*RR;
        if (masks[e] > 0.5f)
            atomicOr(&smb[lhs*4 + (r >> 5)], 1u << (r & 31));
    }
    __syncthreads();
    if (tid < NLHS*4) mb[tid] = smb[tid];
}

struct BceShared {
    unsigned char sidx[4][ROWS_PER_WAVE];       // per-wave one-hot idx
    float         sm_red[4];
};
struct MomShared {
    float sdot[4][64];
    float ssum[4];
};
union SharedU { BceShared b; MomShared m; };

__global__ __launch_bounds__(256, 4) void fused_kernel(
    const float* __restrict__ model,
    const float* __restrict__ target,
    const int*   __restrict__ ind_to_lhs,
    const float* __restrict__ mu,
    const unsigned int* __restrict__ mb,
    double* __restrict__ partials)
{
    __shared__ SharedU sh;
    const int tid = threadIdx.x;

    if (blockIdx.x < NMOM) {
        // ---------------- mom path: var[:,j] for j = blockIdx (verbatim) ----
        const int j    = blockIdx.x;
        const int w    = tid >> 6;
        const int lane = tid & 63;
        const int i    = (lane < ZZ) ? lane : 0;
        float dot = 0.f, s1 = 0.f;
        const int b0 = 256*w;
        #pragma unroll 4
        for (int b = b0; b < b0 + 256; ++b) {
            const float c = mu[b*ZZ + j];     // wave-uniform broadcast
            const float a = mu[b*ZZ + i];     // coalesced across lanes
            dot = fmaf(a, c, dot);
            s1 += c;
        }
        sh.m.sdot[w][lane] = dot;
        if (lane == 0) sh.m.ssum[w] = s1;
        __syncthreads();
        if (w == 0) {
            float term = 0.f;
            if (lane < ZZ) {
                const float var = (sh.m.sdot[0][lane]+sh.m.sdot[1][lane]+sh.m.sdot[2][lane]+sh.m.sdot[3][lane]) * (1.f/BB);
                const float ve  = var - ((lane == j) ? 1.f : 0.f);
                term = tanhf(ve) * ve * (1.f/(ZZ*ZZ));
                if (lane == j) {
                    const float am = (sh.m.ssum[0]+sh.m.ssum[1]+sh.m.ssum[2]+sh.m.ssum[3]) * (1.f/BB);
                    term = fmaf(am*am, 1.f/ZZ, term);
                }
            }
            #pragma unroll
            for (int off = 32; off; off >>= 1) term += __shfl_xor(term, off, 64);
            if (lane == 0) partials[blockIdx.x] = (double)term;
        }
        return;
    }

    // ---------------- bce path: 4 autonomous waves, 64 rows each ------------
    const int bce_blk = blockIdx.x - NMOM;
    const int w    = tid >> 6;
    const int lane = tid & 63;
    const size_t blk_base = (size_t)bce_blk * BLK_ELEMS;

    sh.b.sidx[w][lane] = 0;   // safety (one-hot always overwrites)

    // ---- phase 1: this wave's targets -> one-hot scan (t dies after).
    // A float4 never straddles rows (76 = 19 f4); one writer per row.
    {
        const float4* t4 = (const float4*)(target + blk_base) + w*F4WAVE;
        float4 t[F4ROW];
        #pragma unroll
        for (int k = 0; k < F4ROW; ++k) t[k] = t4[k*64 + lane];
        #pragma unroll
        for (int k = 0; k < F4ROW; ++k) {
            const int v4 = w*F4WAVE + k*64 + lane;    // block-local f4 index
            const float4 tv = t[k];
            int he = -1;
            const int e = v4*4;
            if (tv.x > 0.5f) he = e;
            if (tv.y > 0.5f) he = e+1;
            if (tv.z > 0.5f) he = e+2;
            if (tv.w > 0.5f) he = e+3;
            if (he >= 0) {
                const int row = he / RR;              // in [w*64, w*64+64)
                sh.b.sidx[w][row - w*ROWS_PER_WAVE] = (unsigned char)(he - row*RR);
            }
        }
    }

    // Row parameters: sidx from wave-local LDS (program order, R8-proven),
    // then tiny global gathers (384B bitmap + 304B lhs table, L1-hot).
    const int true_r = (int)sh.b.sidx[w][lane];
    const int lhs    = ind_to_lhs[true_r];
    const unsigned int mw0 = mb[lhs*4 + 0];
    const unsigned int mw1 = mb[lhs*4 + 1];
    const unsigned int mw2 = mb[lhs*4 + 2];

    // ---- phase 2: model row -> registers via opaque asm loads (coalesced:
    // lane-consecutive float4 within the wave's 64-row span).
    float4 x[F4ROW];
    {
        const float* g = (const float*)((const float4*)(model + blk_base) + w*F4WAVE);
        #pragma unroll
        for (int k = 0; k < F4ROW; ++k)
            x[k] = gload16(g + (k*64 + lane)*4);
    }
    asm volatile("s_waitcnt vmcnt(0)" ::: "memory");
    __builtin_amdgcn_sched_barrier(0);

    // --- per-row compute from registers (verbatim R5/R8/R9 op sequence) ---

    // Pass A: masked row max.
    float mx = -1e30f;
    #pragma unroll
    for (int k = 0; k < F4ROW; ++k) {
        const float4 v = x[k];
        #pragma unroll
        for (int c = 0; c < 4; ++c) {
            const int r = k*4 + c;
            const unsigned int mw = (r < 32) ? mw0 : ((r < 64) ? mw1 : mw2);
            const bool un = (mw >> (r & 31)) & 1u;
            const float xm = un ? (&v.x)[c] : -1e30f;
            mx = fmaxf(mx, xm);
        }
    }

    // Pass B: e_r = exp(x_r - mx) (masked -> 0), sum.
    float s = 0.f;
    #pragma unroll
    for (int k = 0; k < F4ROW; ++k) {
        const float4 v = x[k];
        #pragma unroll
        for (int c = 0; c < 4; ++c) {
            const int r = k*4 + c;
            const unsigned int mw = (r < 32) ? mw0 : ((r < 64) ? mw1 : mw2);
            const bool un = (mw >> (r & 31)) & 1u;
            const float xm = un ? (&v.x)[c] : -1e30f;
            s += __expf(xm - mx);
        }
    }

    // Pass C: clamped log(1-p) over ALL r (log2-domain), plus p at target.
    const float inv = 1.f / s;
    float sum_l2 = 0.f;
    float p_true = 0.f;
    #pragma unroll
    for (int k = 0; k < F4ROW; ++k) {
        const float4 v = x[k];
        #pragma unroll
        for (int c = 0; c < 4; ++c) {
            const int r = k*4 + c;
            const unsigned int mw = (r < 32) ? mw0 : ((r < 64) ? mw1 : mw2);
            const bool un = (mw >> (r & 31)) & 1u;
            const float xm = un ? (&v.x)[c] : -1e30f;
            const float ev = __expf(xm - mx);
            const float p  = ev * inv;
            const float l2 = __log2f(1.f - p);
            sum_l2 += fmaxf(l2, NLN2F);
            if (r == true_r) p_true = p;
        }
    }
    float row_sum = LN2F * sum_l2;
    // Swap the true_r element's non-target term for the target term.
    const float l1c_t = fmaxf(LN2F * __log2f(1.f - p_true), -100.f);
    const float lp_t  = fmaxf(__logf(p_true), -100.f);   // p_true==0 (masked) -> -100
    row_sum += lp_t - l1c_t;

    // Block reduce (identical grouping: wave butterfly, (s0+s1)+(s2+s3)).
    #pragma unroll
    for (int off = 32; off; off >>= 1) row_sum += __shfl_xor(row_sum, off, 64);
    if (lane == 0) sh.b.sm_red[w] = row_sum;
    __syncthreads();   // only block-wide barrier; nothing left outstanding
    if (tid == 0)
        partials[blockIdx.x] = (double)((sh.b.sm_red[0] + sh.b.sm_red[1]) + (sh.b.sm_red[2] + sh.b.sm_red[3]));
}

// Sum NBCE bce partials + NMOM mom partials with the right scales. (Unchanged.)
__global__ __launch_bounds__(256) void final_kernel(
    const double* __restrict__ partials, float* __restrict__ out)
{
    __shared__ double sred[4];
    const int tid = threadIdx.x;
    double s = 0.0;
    for (int k = NMOM + tid; k < NBLK; k += 256) s += partials[k];
    double m = (tid < NMOM) ? partials[tid] : 0.0;
    double val = s * (-(double)SS / TOTAL_ELEMS) + m;
    #pragma unroll
    for (int off = 32; off; off >>= 1) val += __shfl_xor(val, off, 64);
    if ((tid & 63) == 0) sred[tid >> 6] = val;
    __syncthreads();
    if (tid == 0) out[0] = (float)((sred[0] + sred[1]) + (sred[2] + sred[3]));
}

extern "C" void kernel_launch(void* const* d_in, const int* in_sizes, int n_in,
                              void* d_out, int out_size, void* d_ws, size_t ws_size,
                              hipStream_t stream) {
    const float* model  = (const float*)d_in[0];   // [B,S,R]
    const float* mu     = (const float*)d_in[1];   // [B,Z]
    // d_in[2] = log_var — unused by the reference output
    const float* target = (const float*)d_in[3];   // [B,S,R] one-hot
    const float* masks  = (const float*)d_in[4];   // [NLHS,R]
    const int*   ind    = (const int*)  d_in[5];   // [R]
    float* out  = (float*)d_out;

    // Workspace: [0..NBLK) double partials, then the 96-word mask bitmap.
    double*       acc = (double*)d_ws;
    unsigned int* mb  = (unsigned int*)((char*)d_ws + (size_t)NBLK * sizeof(double));

    setup_kernel<<<1, 256, 0, stream>>>(masks, mb);
    fused_kernel<<<NBLK, 256, 0, stream>>>(model, target, ind, mu, mb, acc);
    final_kernel<<<1, 256, 0, stream>>>(acc, out);
}